// Round 2
// baseline (330.674 us; speedup 1.0000x reference)
//
#include <hip/hip_runtime.h>

#define B_ROWS 8192
#define IN_F 512
#define OUT_F 1024
#define K_TOT 1536

#define BM 64
#define BN 64
#define BK 64
#define NITER (K_TOT / BK)          // 24

#define W4_COUNT (OUT_F * (K_TOT / 4))   // 393,216 float4s

typedef short bfrag __attribute__((ext_vector_type(8)));   // 8 bf16 = 4 VGPRs
typedef float f4    __attribute__((ext_vector_type(4)));

// round-to-nearest-even fp32 -> bf16, packed pairwise into a dword (for W)
__device__ __forceinline__ unsigned int pack2bf_rne(float a, float b) {
    unsigned int ua = __float_as_uint(a);
    unsigned int ub = __float_as_uint(b);
    ua = (ua + 0x7fffu + ((ua >> 16) & 1u)) >> 16;
    ub = (ub + 0x7fffu + ((ub >> 16) & 1u)) & 0xffff0000u;
    return ua | ub;
}

// truncation pack — EXACT for binary 0.0/1.0 inputs (spikes, z): low 16
// mantissa bits of 0.0f/1.0f are zero, so >>16 is the exact bf16.
__device__ __forceinline__ unsigned int pack2bf_trunc(float a, float b) {
    return (__float_as_uint(a) >> 16) | (__float_as_uint(b) & 0xffff0000u);
}

// ---------------- pass 1: fp32 -> bf16 precast, W ONLY ---------------------
// W_bf16[1024][1536] = [Wi | Wr].  A is converted in-kernel (binary -> exact).
__global__ __launch_bounds__(256) void precast_w(
    const float* __restrict__ Wi, const float* __restrict__ Wr,
    unsigned short* __restrict__ Wbf)
{
    const int idx = blockIdx.x * 256 + threadIdx.x;   // float4 index < W4_COUNT
    const int row = idx / 384, c4 = idx - row * 384;
    const float* src = (c4 < 128) ? Wi + (size_t)row * IN_F + c4 * 4
                                  : Wr + (size_t)row * OUT_F + (c4 - 128) * 4;
    const float4 v = *(const float4*)src;
    uint2 pk = { pack2bf_rne(v.x, v.y), pack2bf_rne(v.z, v.w) };
    *(uint2*)(Wbf + (size_t)idx * 4) = pk;
}

// ---------------- pass 2: bf16 GEMM + fused LSNN ---------------------------
// 64x64 tile (proven 8-blocks/CU geometry) + T3 2-phase pipeline:
//   - A (binary spikes|z) is reg-staged from fp32 and trunc-packed to bf16,
//     ds_write_b128 into XOR-swizzled LDS (slot = c ^ (r&7), as before).
//   - W staged via global_load_lds from the pre-swizzled bf16 buffer.
//   - Double-buffered LDS; per iter ONE raw s_barrier with a COUNTED
//     s_waitcnt vmcnt(4): waits only the 2 W gload_lds (oldest), leaves the
//     4 A-prefetch loads in flight across the barrier (T4). sched_barrier(0)
//     pins W-before-A issue order (vmcnt is FIFO) and stops the prefetch
//     sinking below the waitcnt.
__global__ __launch_bounds__(256, 4) void lsnn_gemm(
    const float* __restrict__ spikes,         // [8192, 512] fp32 binary
    const float* __restrict__ zin,            // [8192, 1024] fp32 binary
    const unsigned short* __restrict__ Wbf,   // [1024, 1536] bf16
    const float* __restrict__ vin,
    const float* __restrict__ iin,
    const float* __restrict__ bin,
    float* __restrict__ out)                  // [4, B, 1024]
{
    __shared__ unsigned short As[2][BM * BK];   // 2 x 8 KB
    __shared__ unsigned short Ws[2][BN * BK];   // 2 x 8 KB

    const int tid = threadIdx.x;
    const int bid = blockIdx.x;
    // bid&15 -> n-tile: XCD = bid%8 sees n-tiles {j, j+8} only -> W slices
    // L2-pinned per XCD for the whole dispatch.
    const int n0 = (bid & 15) * BN;
    const int m0 = (bid >> 4) * BM;

    const int lane = tid & 63;
    const int wave = tid >> 6;
    const int wm = (wave >> 1) * 32;   // 2x2 wave grid over 64x64
    const int wn = (wave & 1) * 32;
    const int lr = lane & 15;
    const int lq = lane >> 4;

    f4 acc[2][2];
    #pragma unroll
    for (int a = 0; a < 2; ++a)
        #pragma unroll
        for (int b = 0; b < 2; ++b)
            acc[a][b] = (f4)0.0f;

    // ---- W staging geometry (global_load_lds, source pre-swizzled) ----
    const unsigned short* Wb = Wbf + (size_t)n0 * K_TOT;
    int wr_[2], wc_[2], wj_[2];
    #pragma unroll
    for (int p = 0; p < 2; ++p) {
        const int q = p * 256 + wave * 64 + lane;   // chunk 0..511
        wr_[p] = q >> 3;
        wc_[p] = (q & 7) ^ (wr_[p] & 7);
        wj_[p] = p * 256 + wave * 64;
    }

    // ---- A staging geometry (reg-staged) ----
    // thread -> row ar (0..63), quarter aq (16 floats of the 64-wide K-slab)
    const int ar = tid >> 2;
    const int aq = tid & 3;
    const float* aS = spikes + (size_t)(m0 + ar) * IN_F  + aq * 16;
    const float* aZ = zin    + (size_t)(m0 + ar) * OUT_F + aq * 16;
    const int s0 = (((aq * 2 + 0) ^ (ar & 7)) << 3);   // swizzled chunk slots
    const int s1 = (((aq * 2 + 1) ^ (ar & 7)) << 3);
    const int arow = ar * BK;

    // prologue: issue A(0) loads (kt = 0 < IN_F -> spikes)
    {
        const float4* ap = (const float4*)aS;
        // fallthrough into loop; regs a0..a3 carry tile t into iteration t
    }
    const float4* ap0 = (const float4*)aS;
    float4 a0 = ap0[0], a1 = ap0[1], a2 = ap0[2], a3 = ap0[3];

    int cur = 0;
    for (int it = 0; it < NITER; ++it) {
        const int kt = it * BK;
        __builtin_amdgcn_sched_barrier(0);   // loop-head pin: nothing crosses

        // phase 1: convert A(t) -> As[cur] (compiler inserts exact vmcnt
        // for a0..a3 here; W loads from t-1 are already drained)
        uint4 pk0, pk1;
        pk0.x = pack2bf_trunc(a0.x, a0.y); pk0.y = pack2bf_trunc(a0.z, a0.w);
        pk0.z = pack2bf_trunc(a1.x, a1.y); pk0.w = pack2bf_trunc(a1.z, a1.w);
        pk1.x = pack2bf_trunc(a2.x, a2.y); pk1.y = pack2bf_trunc(a2.z, a2.w);
        pk1.z = pack2bf_trunc(a3.x, a3.y); pk1.w = pack2bf_trunc(a3.z, a3.w);
        *(uint4*)&As[cur][arow + s0] = pk0;
        *(uint4*)&As[cur][arow + s1] = pk1;
        __builtin_amdgcn_sched_barrier(0);

        // phase 2: W(t) via global_load_lds — MUST issue before A prefetch
        #pragma unroll
        for (int p = 0; p < 2; ++p) {
            __builtin_amdgcn_global_load_lds(
                (const __attribute__((address_space(1))) void*)(Wb + (size_t)wr_[p] * K_TOT + kt + wc_[p] * 8),
                (__attribute__((address_space(3))) void*)(&Ws[cur][wj_[p] * 8]),
                16, 0, 0);
        }
        __builtin_amdgcn_sched_barrier(0);

        // phase 3: A(t+1) prefetch into regs (wraps to 0 on last iter so the
        // vmcnt bookkeeping stays uniform; the wrapped data is never used)
        const int kn = (it + 1 < NITER) ? kt + BK : 0;
        const float4* an = (const float4*)((kn < IN_F) ? (aS + kn) : (aZ + (kn - IN_F)));
        a0 = an[0]; a1 = an[1]; a2 = an[2]; a3 = an[3];
        __builtin_amdgcn_sched_barrier(0);

        // phase 4: counted drain. Outstanding = 2 W (oldest) + 4 A (newest).
        // vmcnt(4) retires exactly the W pair; A stays in flight across the
        // barrier and is absorbed by next iteration's convert.
        asm volatile("s_waitcnt vmcnt(4) lgkmcnt(0)" ::: "memory");
        __builtin_amdgcn_s_barrier();

        // phase 5: MFMA on buffer cur
        #pragma unroll
        for (int ks = 0; ks < 2; ++ks) {
            const int cc = ks * 4 + lq;
            bfrag af[2], wf[2];
            #pragma unroll
            for (int t = 0; t < 2; ++t) {
                const int row = wm + t * 16 + lr;
                af[t] = *(const bfrag*)&As[cur][row * BK + ((cc ^ (row & 7)) << 3)];
            }
            #pragma unroll
            for (int t = 0; t < 2; ++t) {
                const int row = wn + t * 16 + lr;
                wf[t] = *(const bfrag*)&Ws[cur][row * BK + ((cc ^ (row & 7)) << 3)];
            }
            #pragma unroll
            for (int tm = 0; tm < 2; ++tm)
                #pragma unroll
                for (int tn = 0; tn < 2; ++tn)
                    acc[tm][tn] = __builtin_amdgcn_mfma_f32_16x16x32_bf16(
                        af[tm], wf[tn], acc[tm][tn], 0, 0, 0);
        }
        cur ^= 1;
    }

    // Epilogue: C/D mapping col = lane&15, row = (lane>>4)*4 + reg (m89/m91)
    const size_t PL = (size_t)B_ROWS * OUT_F;
    #pragma unroll
    for (int tm = 0; tm < 2; ++tm) {
        #pragma unroll
        for (int tn = 0; tn < 2; ++tn) {
            #pragma unroll
            for (int r = 0; r < 4; ++r) {
                const int gm = m0 + wm + tm * 16 + lq * 4 + r;
                const int gn = n0 + wn + tn * 16 + lr;
                const size_t idx = (size_t)gm * OUT_F + gn;
                const float v = vin[idx];
                const float i = iin[idx];
                const float b = bin[idx];
                const float v_dec = v + 0.1f * ((0.0f - v) + i);   // dt*tau_mem_inv
                const float i_dec = i - 0.2f * i;                  // dt*tau_syn_inv
                const float b_dec = b + 1.25e-06f * (1.0f - b);    // dt*tau_adapt_inv
                const float zn = (v_dec - b_dec > 0.0f) ? 1.0f : 0.0f;
                const float vn = (1.0f - zn) * v_dec;              // v_reset = 0
                const float inew = i_dec + acc[tm][tn][r];
                const float bnew = b_dec + zn * 0.00225f;          // tau_adapt_inv*beta
                out[idx]          = zn;
                out[PL + idx]     = vn;
                out[2 * PL + idx] = inew;
                out[3 * PL + idx] = bnew;
            }
        }
    }
}

extern "C" void kernel_launch(void* const* d_in, const int* in_sizes, int n_in,
                              void* d_out, int out_size, void* d_ws, size_t ws_size,
                              hipStream_t stream) {
    const float* spikes = (const float*)d_in[0];
    const float* z      = (const float*)d_in[1];
    const float* v      = (const float*)d_in[2];
    const float* i      = (const float*)d_in[3];
    const float* b      = (const float*)d_in[4];
    const float* Wi     = (const float*)d_in[5];
    const float* Wr     = (const float*)d_in[6];
    float* out = (float*)d_out;

    unsigned short* Wbf = (unsigned short*)d_ws;   // 3,145,728 B

    precast_w<<<W4_COUNT / 256, 256, 0, stream>>>(Wi, Wr, Wbf);   // 1536 blocks

    const int grid = (B_ROWS / BM) * (OUT_F / BN);                // 2048
    lsnn_gemm<<<grid, 256, 0, stream>>>(spikes, z, Wbf, v, i, b, out);
}

// Round 4
// 308.546 us; speedup vs baseline: 1.0717x; 1.0717x over previous
//
#include <hip/hip_runtime.h>

#define B_ROWS 8192
#define IN_F 512
#define OUT_F 1024
#define K_TOT 1536

#define BM 64
#define BN 64
#define BK 64
#define NITER (K_TOT / BK)          // 24

#define A4_COUNT (B_ROWS * (K_TOT / 4))       // 3,145,728 float4 tasks
#define W4_COUNT (OUT_F  * (K_TOT / 4))       //   393,216
#define P4_COUNT (B_ROWS * OUT_F / 4)         // 2,097,152 pointwise tasks
#define PRE_TASKS (A4_COUNT + W4_COUNT + P4_COUNT)   // 5,636,096 = 22016*256

typedef short bfrag __attribute__((ext_vector_type(8)));   // 8 bf16 = 4 VGPRs
typedef float f4    __attribute__((ext_vector_type(4)));

// round-to-nearest-even fp32 -> bf16, packed pairwise into a dword
__device__ __forceinline__ unsigned int pack2bf(float a, float b) {
    unsigned int ua = __float_as_uint(a);
    unsigned int ub = __float_as_uint(b);
    ua = (ua + 0x7fffu + ((ua >> 16) & 1u)) >> 16;
    ub = (ub + 0x7fffu + ((ub >> 16) & 1u)) & 0xffff0000u;
    return ua | ub;
}

// ---------------- pass 1: precast A/W + streaming pointwise planes ---------
// A_bf16[8192][1536] = [spikes | z], W_bf16[1024][1536] = [Wi | Wr].
// Additionally computes the GEMM-independent output planes z/v/b (planes
// 0,1,3) as a fully-coalesced float4 stream — this kernel shape runs at
// ~6.4 TB/s (measured R0: 141 MB in ~22 us), so 192 MB of epilogue traffic
// moves here from the latency-bound gemm.
__global__ __launch_bounds__(256) void precast_pointwise(
    const float* __restrict__ spikes, const float* __restrict__ zin,
    const float* __restrict__ Wi,     const float* __restrict__ Wr,
    const float* __restrict__ vin,    const float* __restrict__ iin,
    const float* __restrict__ bin,
    unsigned short* __restrict__ Abf, unsigned short* __restrict__ Wbf,
    float* __restrict__ out)
{
    const int idx = blockIdx.x * 256 + threadIdx.x;
    if (idx < A4_COUNT + W4_COUNT) {
        const float* src;
        unsigned short* dst;
        if (idx < A4_COUNT) {
            const int row = idx / 384, c4 = idx - row * 384;
            src = (c4 < 128) ? spikes + (size_t)row * IN_F + c4 * 4
                             : zin    + (size_t)row * OUT_F + (c4 - 128) * 4;
            dst = Abf + (size_t)idx * 4;
        } else {
            const int w = idx - A4_COUNT;
            const int row = w / 384, c4 = w - row * 384;
            src = (c4 < 128) ? Wi + (size_t)row * IN_F + c4 * 4
                             : Wr + (size_t)row * OUT_F + (c4 - 128) * 4;
            dst = Wbf + (size_t)w * 4;
        }
        const float4 v = *(const float4*)src;
        uint2 pk = { pack2bf(v.x, v.y), pack2bf(v.z, v.w) };
        *(uint2*)dst = pk;
    } else {
        const int j = idx - (A4_COUNT + W4_COUNT);   // float4 index into [B,OUT_F]
        const size_t PL = (size_t)B_ROWS * OUT_F;
        const float4 v = ((const float4*)vin)[j];
        const float4 i = ((const float4*)iin)[j];
        const float4 b = ((const float4*)bin)[j];
        float4 z, vn, bn;
        {
            const float v_dec = v.x + 0.1f * ((0.0f - v.x) + i.x);
            const float b_dec = b.x + 1.25e-06f * (1.0f - b.x);
            z.x = (v_dec - b_dec > 0.0f) ? 1.0f : 0.0f;
            vn.x = (1.0f - z.x) * v_dec;
            bn.x = b_dec + z.x * 0.00225f;
        }
        {
            const float v_dec = v.y + 0.1f * ((0.0f - v.y) + i.y);
            const float b_dec = b.y + 1.25e-06f * (1.0f - b.y);
            z.y = (v_dec - b_dec > 0.0f) ? 1.0f : 0.0f;
            vn.y = (1.0f - z.y) * v_dec;
            bn.y = b_dec + z.y * 0.00225f;
        }
        {
            const float v_dec = v.z + 0.1f * ((0.0f - v.z) + i.z);
            const float b_dec = b.z + 1.25e-06f * (1.0f - b.z);
            z.z = (v_dec - b_dec > 0.0f) ? 1.0f : 0.0f;
            vn.z = (1.0f - z.z) * v_dec;
            bn.z = b_dec + z.z * 0.00225f;
        }
        {
            const float v_dec = v.w + 0.1f * ((0.0f - v.w) + i.w);
            const float b_dec = b.w + 1.25e-06f * (1.0f - b.w);
            z.w = (v_dec - b_dec > 0.0f) ? 1.0f : 0.0f;
            vn.w = (1.0f - z.w) * v_dec;
            bn.w = b_dec + z.w * 0.00225f;
        }
        ((float4*)out)[j]            = z;    // plane 0
        ((float4*)(out + PL))[j]     = vn;   // plane 1
        ((float4*)(out + 3 * PL))[j] = bn;   // plane 3
    }
}

// ---------------- pass 2: bf16 GEMM + i-plane epilogue ---------------------
// R0's proven 64x64 geometry (XOR-swizzled gload_lds, 0 bank conflicts) +
// T3 minimum 2-phase pipeline: double-buffered LDS, STAGE(t+1) issued
// BEFORE the MFMA phase, single __syncthreads() per iter at the END (its
// vmcnt(0)+lgkmcnt(0)+barrier drain is exactly the tile-(t+1) completion
// wait, now overlapped with compute instead of preceding it). No
// sched_barrier pins (m141/R2 lesson).
__global__ __launch_bounds__(256, 4) void lsnn_gemm(
    const unsigned short* __restrict__ Abf,   // [8192, 1536] bf16
    const unsigned short* __restrict__ Wbf,   // [1024, 1536] bf16
    const float* __restrict__ iin,
    float* __restrict__ out)                  // writes plane 2 only
{
    __shared__ unsigned short As[2][BM * BK];   // 2 x 8 KB
    __shared__ unsigned short Ws[2][BN * BK];   // 2 x 8 KB

    const int tid = threadIdx.x;
    const int bid = blockIdx.x;
    // bid&15 -> n-tile: XCD = bid%8 sees n-tiles {j, j+8} only -> 2 W slices
    // (2 x 192 KB) pinned per XCD L2 for the whole dispatch.
    const int n0 = (bid & 15) * BN;
    const int m0 = (bid >> 4) * BM;

    const int lane = tid & 63;
    const int wave = tid >> 6;
    const int wm = (wave >> 1) * 32;   // 2x2 wave grid over 64x64
    const int wn = (wave & 1) * 32;
    const int lr = lane & 15;
    const int lq = lane >> 4;

    f4 acc[2][2];
    #pragma unroll
    for (int a = 0; a < 2; ++a)
        #pragma unroll
        for (int b = 0; b < 2; ++b)
            acc[a][b] = (f4)0.0f;

    const unsigned short* Ab = Abf + (size_t)m0 * K_TOT;
    const unsigned short* Wb = Wbf + (size_t)n0 * K_TOT;

    // Per-lane staging geometry (row r, swizzled source chunk c), constant
    // across K; 8 consecutive rows x 8 lanes cover all 8 swizzled 16B slots
    // -> 8x128B coalesced global segments per inst.
    int rr[2], cc_[2], jj[2];
    #pragma unroll
    for (int p = 0; p < 2; ++p) {
        const int q = p * 256 + wave * 64 + lane;   // chunk 0..511
        rr[p] = q >> 3;
        cc_[p] = (q & 7) ^ (rr[p] & 7);
        jj[p] = p * 256 + wave * 64;
    }

    auto stage = [&](int buf, int kt) {
        #pragma unroll
        for (int p = 0; p < 2; ++p)
            __builtin_amdgcn_global_load_lds(
                (const __attribute__((address_space(1))) void*)(Ab + (size_t)rr[p] * K_TOT + kt + cc_[p] * 8),
                (__attribute__((address_space(3))) void*)(&As[buf][jj[p] * 8]),
                16, 0, 0);
        #pragma unroll
        for (int p = 0; p < 2; ++p)
            __builtin_amdgcn_global_load_lds(
                (const __attribute__((address_space(1))) void*)(Wb + (size_t)rr[p] * K_TOT + kt + cc_[p] * 8),
                (__attribute__((address_space(3))) void*)(&Ws[buf][jj[p] * 8]),
                16, 0, 0);
    };

    // prologue: tile 0
    stage(0, 0);
    __syncthreads();

    int cur = 0;
    for (int it = 0; it < NITER; ++it) {
        // phase 1: issue next tile's staging (skipped on last iter)
        if (it + 1 < NITER) stage(cur ^ 1, (it + 1) * BK);

        // phase 2: compute on current buffer (compiler inserts lgkmcnt for
        // ds_read->MFMA; the gload_lds above stay in flight underneath)
        #pragma unroll
        for (int ks = 0; ks < 2; ++ks) {
            const int cc = ks * 4 + lq;
            bfrag af[2], wf[2];
            #pragma unroll
            for (int t = 0; t < 2; ++t) {
                const int row = wm + t * 16 + lr;
                af[t] = *(const bfrag*)&As[cur][row * BK + ((cc ^ (row & 7)) << 3)];
            }
            #pragma unroll
            for (int t = 0; t < 2; ++t) {
                const int row = wn + t * 16 + lr;
                wf[t] = *(const bfrag*)&Ws[cur][row * BK + ((cc ^ (row & 7)) << 3)];
            }
            #pragma unroll
            for (int tm = 0; tm < 2; ++tm)
                #pragma unroll
                for (int tn = 0; tn < 2; ++tn)
                    acc[tm][tn] = __builtin_amdgcn_mfma_f32_16x16x32_bf16(
                        af[tm], wf[tn], acc[tm][tn], 0, 0, 0);
        }

        // phase 3: drain tile t+1 (vmcnt(0)) + barrier — after compute, so
        // staging latency is hidden under the MFMA/ds_read phase.
        __syncthreads();
        cur ^= 1;
    }

    // Epilogue: only the GEMM-dependent plane (i_new = i_decayed + acc).
    // C/D mapping col = lane&15, row = (lane>>4)*4 + reg (m89/m91).
    const size_t PL2 = 2 * (size_t)B_ROWS * OUT_F;
    #pragma unroll
    for (int tm = 0; tm < 2; ++tm) {
        #pragma unroll
        for (int tn = 0; tn < 2; ++tn) {
            #pragma unroll
            for (int r = 0; r < 4; ++r) {
                const int gm = m0 + wm + tm * 16 + lq * 4 + r;
                const int gn = n0 + wn + tn * 16 + lr;
                const size_t idx = (size_t)gm * OUT_F + gn;
                const float i = iin[idx];
                out[PL2 + idx] = (i - 0.2f * i) + acc[tm][tn][r];
            }
        }
    }
}

extern "C" void kernel_launch(void* const* d_in, const int* in_sizes, int n_in,
                              void* d_out, int out_size, void* d_ws, size_t ws_size,
                              hipStream_t stream) {
    const float* spikes = (const float*)d_in[0];
    const float* z      = (const float*)d_in[1];
    const float* v      = (const float*)d_in[2];
    const float* i      = (const float*)d_in[3];
    const float* b      = (const float*)d_in[4];
    const float* Wi     = (const float*)d_in[5];
    const float* Wr     = (const float*)d_in[6];
    float* out = (float*)d_out;

    unsigned short* Abf = (unsigned short*)d_ws;                       // 25,165,824 B
    unsigned short* Wbf = Abf + (size_t)B_ROWS * K_TOT;                //  3,145,728 B

    precast_pointwise<<<PRE_TASKS / 256, 256, 0, stream>>>(
        spikes, z, Wi, Wr, v, i, b, Abf, Wbf, out);                    // 22016 blocks

    const int grid = (B_ROWS / BM) * (OUT_F / BN);                     // 2048
    lsnn_gemm<<<grid, 256, 0, stream>>>(Abf, Wbf, i, out);
}